// Round 6
// baseline (407.304 us; speedup 1.0000x reference)
//
#include <hip/hip_runtime.h>
#include <math.h>

typedef __bf16 bf16_t;
typedef __bf16 bf16x8 __attribute__((ext_vector_type(8)));
typedef float f32x4 __attribute__((ext_vector_type(4)));

#define B_INS 8192
#define N_INS 16384
#define D 128
#define BP 256
#define P 256
#define NP 512

// exp(l-10) with l = dot*10  ==  exp2(dot*C1 - C1), C1 = 10*log2(e)
#define C1_CONST 14.426950408889634f

// ---------------- workspace layout (floats) ----------------
// acc[0]=ins sum, acc[1]=patch sum, acc[2]=n_valid
#define WS_ACC 0
#define WS_S 8
#define WS_POS (8 + 16384)
#define WS_SP (8 + 2 * 16384)
#define WS_PP (WS_SP + BP * NP)
#define WS_ZERO_FLOATS (WS_PP + BP * NP)
#define EMB_I_BYTE ((((WS_ZERO_FLOATS) * 4 + 15) / 16) * 16)
#define EMB_P_BYTE (EMB_I_BYTE + N_INS * D * 2)

// Panel layout: global row i, k -> panel p=i>>7, r=i&127, g=k>>3, j=k&7
// elem offset = (p<<14) + (g<<10) + (r<<3) + j. One panel = 16384 elems = 32 KB.
// - register frag loads: 16 tx-lanes at 16B stride -> contiguous 256B runs.
// - LDS ds_read_b128 at (g<<10)+(r<<3): banks (r*4+c)%32, conflict-free (R4-verified).

// ---------------- staging: linear 32 KB panel copy (async, wave-uniform dst) ----
__device__ __forceinline__ void load_lds16(const bf16_t* g, bf16_t* l) {
    __builtin_amdgcn_global_load_lds(
        (const __attribute__((address_space(1))) void*)g,
        (__attribute__((address_space(3))) void*)l, 16, 0, 0);
}

__device__ __forceinline__ void stage_panel(const bf16_t* __restrict__ src,
                                            bf16_t* dst, int w, int lane) {
    const bf16_t* g = src + w * 4096 + lane * 8;
    bf16_t* d = dst + w * 4096;
#pragma unroll
    for (int it = 0; it < 8; it++)
        load_lds16(g + it * 512, d + it * 512);
}

// ---------------- A-fragment register load (from L2, panel layout) -----------
__device__ __forceinline__ void load_afrags(const bf16_t* __restrict__ abase,
                                            int rh, int tx, int q, bf16x8 af[4][4]) {
    const bf16_t* a = abase + ((rh * 64 + tx) << 3);
#pragma unroll
    for (int rt = 0; rt < 4; rt++)
#pragma unroll
        for (int ks = 0; ks < 4; ks++)
            af[rt][ks] = *(const bf16x8*)(a + (((ks << 2) + q) << 10) + (rt << 7));
}

// ---------------- shared epilogue helpers ----------------
__device__ __forceinline__ void flush_rowS(float rowS[16], int rowBase,
                                           int rh, int tx, int q,
                                           float* __restrict__ S) {
#pragma unroll
    for (int off = 1; off <= 8; off <<= 1)
#pragma unroll
        for (int i = 0; i < 16; i++) rowS[i] += __shfl_xor(rowS[i], off, 16);
    if (tx == 0) {
#pragma unroll
        for (int rt = 0; rt < 4; rt++)
#pragma unroll
            for (int reg = 0; reg < 4; reg++)
                atomicAdd(&S[rowBase + rh * 64 + rt * 16 + q * 4 + reg],
                          rowS[rt * 4 + reg]);
    }
}

// ---------------- normalize kernels (write panel layout) ----------------
__global__ __launch_bounds__(256) void norm_ins_k(const float* __restrict__ v1,
                                                  const float* __restrict__ v2,
                                                  bf16_t* __restrict__ embI) {
    int w = threadIdx.x >> 6, lane = threadIdx.x & 63;
    int i = blockIdx.x * 4 + w;
    const float* src = (i < B_INS) ? (v1 + (size_t)i * D) : (v2 + (size_t)(i - B_INS) * D);
    float2 v = *(const float2*)(src + lane * 2);
    float ss = v.x * v.x + v.y * v.y;
#pragma unroll
    for (int off = 32; off >= 1; off >>= 1) ss += __shfl_xor(ss, off, 64);
    float inv = 1.0f / fmaxf(sqrtf(ss), 1e-12f);
    union { bf16_t b[2]; unsigned u; } pk;
    pk.b[0] = (bf16_t)(v.x * inv);
    pk.b[1] = (bf16_t)(v.y * inv);
    size_t off = ((size_t)(i >> 7) << 14) + ((size_t)(lane >> 2) << 10) +
                 ((size_t)(i & 127) << 3) + ((lane & 3) << 1);
    *(unsigned*)(embI + off) = pk.u;
}

__global__ __launch_bounds__(256) void norm_patch_k(const float* __restrict__ v1,
                                                    const float* __restrict__ v2,
                                                    bf16_t* __restrict__ embP) {
    __shared__ float L[128][65];
    __shared__ float ps[4][64];
    __shared__ float invs[64];
    int t = threadIdx.x;
    int bx = blockIdx.x;
    int b = bx >> 3, h = (bx >> 2) & 1, chunk = bx & 3;
    int i0 = chunk * 64;
    const float* src = ((h == 0) ? v1 : v2) + (size_t)b * D * P;

#pragma unroll
    for (int it = 0; it < 8; it++) {
        int fi = it * 256 + t;
        int d = fi >> 4, c4 = fi & 15;
        float4 v = *(const float4*)(src + (size_t)d * P + i0 + c4 * 4);
        L[d][c4 * 4 + 0] = v.x;
        L[d][c4 * 4 + 1] = v.y;
        L[d][c4 * 4 + 2] = v.z;
        L[d][c4 * 4 + 3] = v.w;
    }
    __syncthreads();
    {
        int col = t & 63, part = t >> 6;
        float ss = 0.f;
#pragma unroll 8
        for (int d = part * 32; d < part * 32 + 32; d++) { float x = L[d][col]; ss += x * x; }
        ps[part][col] = ss;
    }
    __syncthreads();
    if (t < 64) {
        float n2 = ps[0][t] + ps[1][t] + ps[2][t] + ps[3][t];
        invs[t] = 1.0f / fmaxf(sqrtf(n2), 1e-12f);
    }
    __syncthreads();
#pragma unroll
    for (int it = 0; it < 16; it++) {
        int idx = it * 256 + t;
        int pc = idx & 63, ic = idx >> 6;
        int d = pc * 2;
        float inv = invs[ic];
        union { bf16_t b[2]; unsigned u; } pk;
        pk.b[0] = (bf16_t)(L[d][ic] * inv);
        pk.b[1] = (bf16_t)(L[d + 1][ic] * inv);
        int iLoc = h * P + i0 + ic;   // row within batch, [0,512)
        size_t off = ((size_t)b << 16) + ((size_t)(iLoc >> 7) << 14) +
                     ((size_t)(pc >> 2) << 10) + ((size_t)(iLoc & 127) << 3) +
                     ((pc & 3) << 1);
        *(unsigned*)(embP + off) = pk.u;
    }
}

// ---------------- instance CE: A in regs, B via LDS, 4-tile balanced chunks ----
__global__ __launch_bounds__(256, 4) void ins_chunk_k(const bf16_t* __restrict__ emb,
                                                      float* __restrict__ S,
                                                      float* __restrict__ pos) {
    __shared__ __align__(16) bf16_t shB[16384];
    int t = threadIdx.x, w = t >> 6, lane = t & 63;
    int tx = lane & 15, q = lane >> 4;
    int rh = w & 1, ch = w >> 1;

    // decode: R-groups of 4 rows share chunk count c = 32 - (R/4).
    // cum(k) = 4*sum_{j<k}(32-j); find k<=31 by scalar loop.
    int bid = blockIdx.x, k = 0, cum = 0;
    while (bid >= cum + 4 * (32 - k)) { cum += 4 * (32 - k); k++; }
    int rem = bid - cum;
    int cc = 32 - k;
    int R = 4 * k + rem / cc;
    int ci = rem - (rem / cc) * cc;
    int c0 = R + ci * 4;
    int ntiles = min(4, 128 - c0);
    int rowBase = R * 128;

    bf16x8 af[4][4];
    load_afrags(emb + ((size_t)R << 14), rh, tx, q, af);

    float rowS[16];
#pragma unroll
    for (int i = 0; i < 16; i++) rowS[i] = 0.f;

    for (int ti = 0; ti < ntiles; ti++) {
        int C = c0 + ti;
        __syncthreads();                       // previous tile's readers done
        stage_panel(emb + ((size_t)C << 14), shB, w, lane);
        __syncthreads();                       // vmcnt drained -> staging visible
        bool isDiag = (C == R), isPos = (C == R + 64);
        int colBase = C * 128;

        float colS[4] = {0.f, 0.f, 0.f, 0.f};
#pragma unroll
        for (int nt = 0; nt < 4; nt++) {
            bf16x8 bf[4];
#pragma unroll
            for (int ks = 0; ks < 4; ks++)
                bf[ks] = *(const bf16x8*)(shB + (((ks << 2) + q) << 10) +
                                          ((ch * 64 + nt * 16 + tx) << 3));
            f32x4 acc[4];
#pragma unroll
            for (int rt = 0; rt < 4; rt++) acc[rt] = (f32x4){0.f, 0.f, 0.f, 0.f};
#pragma unroll
            for (int ks = 0; ks < 4; ks++)
#pragma unroll
                for (int rt = 0; rt < 4; rt++)
                    acc[rt] = __builtin_amdgcn_mfma_f32_16x16x32_bf16(
                        af[rt][ks], bf[ks], acc[rt], 0, 0, 0);
#pragma unroll
            for (int rt = 0; rt < 4; rt++) {
#pragma unroll
                for (int reg = 0; reg < 4; reg++) {
                    float e = __builtin_amdgcn_exp2f(
                        fmaf(acc[rt][reg], C1_CONST, -C1_CONST));
                    if (isDiag) {
                        int inRow = rh * 64 + rt * 16 + q * 4 + reg;
                        int inCol = ch * 64 + nt * 16 + tx;
                        e = (inRow == inCol) ? 0.f : e;
                    }
                    rowS[rt * 4 + reg] += e;
                    colS[nt] += e;
                }
            }
            if (isPos && ch == rh) {
                int reg = tx - q * 4;
                if (reg >= 0 && reg < 4) {
                    float pl = acc[nt][reg] * 10.0f;   // rt==nt diagonal fragment
                    atomicAdd(&pos[rowBase + rh * 64 + nt * 16 + tx], pl);
                    atomicAdd(&pos[colBase + rh * 64 + nt * 16 + tx], pl);
                }
            }
        }
        if (!isDiag) {
#pragma unroll
            for (int i = 0; i < 4; i++) {
                colS[i] += __shfl_xor(colS[i], 16, 64);
                colS[i] += __shfl_xor(colS[i], 32, 64);
            }
            if (q == 0) {
#pragma unroll
                for (int nt = 0; nt < 4; nt++)
                    atomicAdd(&S[colBase + ch * 64 + nt * 16 + tx], colS[nt]);
            }
        }
    }
    flush_rowS(rowS, rowBase, rh, tx, q, S);
}

// ---------------- patch CE: one tile per block, register streaming ----------
__constant__ int RTAB[10] = {0, 0, 0, 0, 1, 1, 1, 2, 2, 3};
__constant__ int CTAB[10] = {0, 1, 2, 3, 1, 2, 3, 2, 3, 3};

__global__ __launch_bounds__(256) void patch_tile_k(const bf16_t* __restrict__ embP,
                                                    float* __restrict__ Sp,
                                                    float* __restrict__ posp) {
    int t = threadIdx.x, w = t >> 6, lane = t & 63;
    int tx = lane & 15, q = lane >> 4;
    int rh = w & 1, ch = w >> 1;
    int R = RTAB[blockIdx.x], C = CTAB[blockIdx.x], b = blockIdx.y;
    const bf16_t* base = embP + ((size_t)b << 16);
    float* Sb = Sp + (size_t)b * NP;
    float* pb = posp + (size_t)b * NP;
    bool isDiag = (C == R), isPos = (C == R + 2);
    int rowBase = R * 128, colBase = C * 128;

    bf16x8 af[4][4];
    load_afrags(base + ((size_t)R << 14), rh, tx, q, af);

    float rowS[16];
#pragma unroll
    for (int i = 0; i < 16; i++) rowS[i] = 0.f;
    float colS[4] = {0.f, 0.f, 0.f, 0.f};

    const bf16_t* bbase = base + ((size_t)C << 14) + ((ch * 64 + tx) << 3);
#pragma unroll
    for (int nt = 0; nt < 4; nt++) {
        bf16x8 bf[4];
#pragma unroll
        for (int ks = 0; ks < 4; ks++)
            bf[ks] = *(const bf16x8*)(bbase + (((ks << 2) + q) << 10) + (nt << 7));
        f32x4 acc[4];
#pragma unroll
        for (int rt = 0; rt < 4; rt++) acc[rt] = (f32x4){0.f, 0.f, 0.f, 0.f};
#pragma unroll
        for (int ks = 0; ks < 4; ks++)
#pragma unroll
            for (int rt = 0; rt < 4; rt++)
                acc[rt] = __builtin_amdgcn_mfma_f32_16x16x32_bf16(
                    af[rt][ks], bf[ks], acc[rt], 0, 0, 0);
#pragma unroll
        for (int rt = 0; rt < 4; rt++) {
#pragma unroll
            for (int reg = 0; reg < 4; reg++) {
                float e = __builtin_amdgcn_exp2f(
                    fmaf(acc[rt][reg], C1_CONST, -C1_CONST));
                if (isDiag) {
                    int inRow = rh * 64 + rt * 16 + q * 4 + reg;
                    int inCol = ch * 64 + nt * 16 + tx;
                    e = (inRow == inCol) ? 0.f : e;
                }
                rowS[rt * 4 + reg] += e;
                colS[nt] += e;
            }
        }
        if (isPos && ch == rh) {
            int reg = tx - q * 4;
            if (reg >= 0 && reg < 4) {
                float pl = acc[nt][reg] * 10.0f;
                atomicAdd(&pb[rowBase + rh * 64 + nt * 16 + tx], pl);
                atomicAdd(&pb[colBase + rh * 64 + nt * 16 + tx], pl);
            }
        }
    }
    if (!isDiag) {
#pragma unroll
        for (int i = 0; i < 4; i++) {
            colS[i] += __shfl_xor(colS[i], 16, 64);
            colS[i] += __shfl_xor(colS[i], 32, 64);
        }
        if (q == 0) {
#pragma unroll
            for (int nt = 0; nt < 4; nt++)
                atomicAdd(&Sb[colBase + ch * 64 + nt * 16 + tx], colS[nt]);
        }
    }
    flush_rowS(rowS, rowBase, rh, tx, q, Sb);
}

// ---------------- finalize ----------------
__global__ void fin_ins_k(const float* __restrict__ S_ins, const float* __restrict__ pos_ins,
                          float* __restrict__ acc) {
    int i = blockIdx.x * 256 + threadIdx.x;
    float v = __logf(S_ins[i]) + 10.0f - pos_ins[i];
    int lane = threadIdx.x & 63, wave = threadIdx.x >> 6;
#pragma unroll
    for (int off = 32; off >= 1; off >>= 1) v += __shfl_down(v, off, 64);
    __shared__ float ps[4];
    if (lane == 0) ps[wave] = v;
    __syncthreads();
    if (threadIdx.x == 0) atomicAdd(&acc[0], ps[0] + ps[1] + ps[2] + ps[3]);
}

// Patch finalize: accumulates BOTH the masked loss sum (acc[1]) and n_valid (acc[2]).
__global__ void fin_patch_k(const float* __restrict__ Sp, const float* __restrict__ posp,
                            const int* __restrict__ c1, const int* __restrict__ c2,
                            float* __restrict__ acc) {
    int idx = blockIdx.x * 256 + threadIdx.x;   // over BP*NP
    int b = idx >> 9, i = idx & 511;
    int cnt = (i < P) ? c1[b * P + i] : c2[b * P + i - P];
    bool valid = (cnt != 0);
    float v = valid ? (__logf(Sp[idx]) + 10.0f - posp[idx]) : 0.f;
    float nv = valid ? 1.0f : 0.0f;
    int lane = threadIdx.x & 63, wave = threadIdx.x >> 6;
#pragma unroll
    for (int off = 32; off >= 1; off >>= 1) {
        v += __shfl_down(v, off, 64);
        nv += __shfl_down(nv, off, 64);
    }
    __shared__ float ps[4], pn[4];
    if (lane == 0) { ps[wave] = v; pn[wave] = nv; }
    __syncthreads();
    if (threadIdx.x == 0) {
        atomicAdd(&acc[1], ps[0] + ps[1] + ps[2] + ps[3]);
        atomicAdd(&acc[2], pn[0] + pn[1] + pn[2] + pn[3]);
    }
}

__global__ void final_k(const float* __restrict__ acc, float* __restrict__ out) {
    out[0] = acc[0] * (1.0f / (float)N_INS) + acc[1] / acc[2];
}

// ---------------- launch ----------------
extern "C" void kernel_launch(void* const* d_in, const int* in_sizes, int n_in,
                              void* d_out, int out_size, void* d_ws, size_t ws_size,
                              hipStream_t stream) {
    const float* v1i = (const float*)d_in[0];
    const float* v2i = (const float*)d_in[1];
    const float* v1p = (const float*)d_in[2];
    const float* v2p = (const float*)d_in[3];
    const int* c1 = (const int*)d_in[4];
    const int* c2 = (const int*)d_in[5];
    float* ws = (float*)d_ws;
    float* out = (float*)d_out;
    bf16_t* embI = (bf16_t*)((char*)d_ws + EMB_I_BYTE);
    bf16_t* embP = (bf16_t*)((char*)d_ws + EMB_P_BYTE);

    hipMemsetAsync(ws, 0, WS_ZERO_FLOATS * sizeof(float), stream);

    norm_ins_k<<<N_INS / 4, 256, 0, stream>>>(v1i, v2i, embI);
    norm_patch_k<<<BP * 2 * 4, 256, 0, stream>>>(v1p, v2p, embP);

    ins_chunk_k<<<2112, 256, 0, stream>>>(embI, ws + WS_S, ws + WS_POS);
    patch_tile_k<<<dim3(10, BP), 256, 0, stream>>>(embP, ws + WS_SP, ws + WS_PP);

    fin_ins_k<<<N_INS / 256, 256, 0, stream>>>(ws + WS_S, ws + WS_POS, ws + WS_ACC);
    fin_patch_k<<<(BP * NP) / 256, 256, 0, stream>>>(ws + WS_SP, ws + WS_PP, c1, c2, ws + WS_ACC);
    final_k<<<1, 64, 0, stream>>>(ws + WS_ACC, out);
}

// Round 7
// 266.517 us; speedup vs baseline: 1.5282x; 1.5282x over previous
//
#include <hip/hip_runtime.h>
#include <math.h>

typedef __bf16 bf16_t;
typedef __bf16 bf16x8 __attribute__((ext_vector_type(8)));
typedef float f32x4 __attribute__((ext_vector_type(4)));

#define B_INS 8192
#define N_INS 16384
#define D 128
#define BP 256
#define P 256
#define NP 512

// exp(l-10) with l = dot*10  ==  exp2(dot*C1 - C1), C1 = 10*log2(e)
#define C1_CONST 14.426950408889634f

// ---------------- workspace layout (floats) ----------------
// acc[0]=ins sum, acc[1]=patch sum, acc[2]=n_valid, acc[3]=ticket (uint)
#define WS_ACC 0
#define WS_S 8
#define WS_POS (8 + 16384)
#define WS_SP (8 + 2 * 16384)
#define WS_PP (WS_SP + BP * NP)
#define WS_ZERO_FLOATS (WS_PP + BP * NP)        // 294920 floats = 73730 float4 exactly
#define EMB_I_BYTE ((((WS_ZERO_FLOATS) * 4 + 15) / 16) * 16)
#define EMB_P_BYTE (EMB_I_BYTE + N_INS * D * 2)

// Panel layout: global row i, k -> panel p=i>>7, r=i&127, g=k>>3, j=k&7
// elem offset = (p<<14) + (g<<10) + (r<<3) + j. One panel = 32 KB contiguous.
// - register frag loads: 16 tx-lanes at 16B stride -> contiguous 256B runs.
// - LDS ds_read_b128 at (g<<10)+(r<<3): banks (r*4+c)%32, conflict-free (R4-verified).

// grid partitioning
#define NB_NORMI 4096
#define NB_NORMP 2048
#define NB_ZERO 289
#define NB_PREP (NB_NORMI + NB_NORMP + NB_ZERO)
#define NB_INS 2112
#define NB_PATCH 2560
#define NB_GRAM (NB_INS + NB_PATCH)
#define NB_FIN 576          // 64 ins + 512 patch

// ---------------- staging: linear 32 KB panel copy (async, wave-uniform dst) ----
__device__ __forceinline__ void load_lds16(const bf16_t* g, bf16_t* l) {
    __builtin_amdgcn_global_load_lds(
        (const __attribute__((address_space(1))) void*)g,
        (__attribute__((address_space(3))) void*)l, 16, 0, 0);
}

__device__ __forceinline__ void stage_panel(const bf16_t* __restrict__ src,
                                            bf16_t* dst, int w, int lane) {
    const bf16_t* g = src + w * 4096 + lane * 8;
    bf16_t* d = dst + w * 4096;
#pragma unroll
    for (int it = 0; it < 8; it++)
        load_lds16(g + it * 512, d + it * 512);
}

// ---------------- A-fragment register load (from L2, panel layout) -----------
__device__ __forceinline__ void load_afrags(const bf16_t* __restrict__ abase,
                                            int rh, int tx, int q, bf16x8 af[4][4]) {
    const bf16_t* a = abase + ((rh * 64 + tx) << 3);
#pragma unroll
    for (int rt = 0; rt < 4; rt++)
#pragma unroll
        for (int ks = 0; ks < 4; ks++)
            af[rt][ks] = *(const bf16x8*)(a + (((ks << 2) + q) << 10) + (rt << 7));
}

__device__ __forceinline__ void flush_rowS(float rowS[16], int rowBase,
                                           int rh, int tx, int q,
                                           float* __restrict__ S) {
#pragma unroll
    for (int off = 1; off <= 8; off <<= 1)
#pragma unroll
        for (int i = 0; i < 16; i++) rowS[i] += __shfl_xor(rowS[i], off, 16);
    if (tx == 0) {
#pragma unroll
        for (int rt = 0; rt < 4; rt++)
#pragma unroll
            for (int reg = 0; reg < 4; reg++)
                atomicAdd(&S[rowBase + rh * 64 + rt * 16 + q * 4 + reg],
                          rowS[rt * 4 + reg]);
    }
}

// ================= kernel 1: prep (norms + workspace zero) =================
__global__ __launch_bounds__(256) void prep_k(const float* __restrict__ v1i,
                                              const float* __restrict__ v2i,
                                              const float* __restrict__ v1p,
                                              const float* __restrict__ v2p,
                                              bf16_t* __restrict__ embI,
                                              bf16_t* __restrict__ embP,
                                              float* __restrict__ ws) {
    __shared__ float L[128][65];
    __shared__ float ps[4][64];
    __shared__ float invs[64];
    int bx = blockIdx.x;
    int t = threadIdx.x;
    if (bx < NB_NORMI) {
        int w = t >> 6, lane = t & 63;
        int i = bx * 4 + w;
        const float* src = (i < B_INS) ? (v1i + (size_t)i * D)
                                       : (v2i + (size_t)(i - B_INS) * D);
        float2 v = *(const float2*)(src + lane * 2);
        float ss = v.x * v.x + v.y * v.y;
#pragma unroll
        for (int off = 32; off >= 1; off >>= 1) ss += __shfl_xor(ss, off, 64);
        float inv = 1.0f / fmaxf(sqrtf(ss), 1e-12f);
        union { bf16_t b[2]; unsigned u; } pk;
        pk.b[0] = (bf16_t)(v.x * inv);
        pk.b[1] = (bf16_t)(v.y * inv);
        size_t off = ((size_t)(i >> 7) << 14) + ((size_t)(lane >> 2) << 10) +
                     ((size_t)(i & 127) << 3) + ((lane & 3) << 1);
        *(unsigned*)(embI + off) = pk.u;
    } else if (bx < NB_NORMI + NB_NORMP) {
        int bx2 = bx - NB_NORMI;
        int b = bx2 >> 3, h = (bx2 >> 2) & 1, chunk = bx2 & 3;
        int i0 = chunk * 64;
        const float* src = ((h == 0) ? v1p : v2p) + (size_t)b * D * P;
#pragma unroll
        for (int it = 0; it < 8; it++) {
            int fi = it * 256 + t;
            int d = fi >> 4, c4 = fi & 15;
            float4 v = *(const float4*)(src + (size_t)d * P + i0 + c4 * 4);
            L[d][c4 * 4 + 0] = v.x;
            L[d][c4 * 4 + 1] = v.y;
            L[d][c4 * 4 + 2] = v.z;
            L[d][c4 * 4 + 3] = v.w;
        }
        __syncthreads();
        {
            int col = t & 63, part = t >> 6;
            float ss = 0.f;
#pragma unroll 8
            for (int d = part * 32; d < part * 32 + 32; d++) { float x = L[d][col]; ss += x * x; }
            ps[part][col] = ss;
        }
        __syncthreads();
        if (t < 64) {
            float n2 = ps[0][t] + ps[1][t] + ps[2][t] + ps[3][t];
            invs[t] = 1.0f / fmaxf(sqrtf(n2), 1e-12f);
        }
        __syncthreads();
#pragma unroll
        for (int it = 0; it < 16; it++) {
            int idx = it * 256 + t;
            int pc = idx & 63, ic = idx >> 6;
            int d = pc * 2;
            float inv = invs[ic];
            union { bf16_t b[2]; unsigned u; } pk;
            pk.b[0] = (bf16_t)(L[d][ic] * inv);
            pk.b[1] = (bf16_t)(L[d + 1][ic] * inv);
            int iLoc = h * P + i0 + ic;
            size_t off = ((size_t)b << 16) + ((size_t)(iLoc >> 7) << 14) +
                         ((size_t)(pc >> 2) << 10) + ((size_t)(iLoc & 127) << 3) +
                         ((pc & 3) << 1);
            *(unsigned*)(embP + off) = pk.u;
        }
    } else {
        int idx = (bx - NB_NORMI - NB_NORMP) * 256 + t;
        if (idx < WS_ZERO_FLOATS / 4)
            ((f32x4*)ws)[idx] = (f32x4){0.f, 0.f, 0.f, 0.f};
    }
}

// ================= kernel 2: fused Gram (ins + patch) =================
__constant__ int RTAB[10] = {0, 0, 0, 0, 1, 1, 1, 2, 2, 3};
__constant__ int CTAB[10] = {0, 1, 2, 3, 1, 2, 3, 2, 3, 3};

__global__ __launch_bounds__(256) void gram_k(const bf16_t* __restrict__ embI,
                                              const bf16_t* __restrict__ embP,
                                              float* __restrict__ S,
                                              float* __restrict__ pos,
                                              float* __restrict__ Sp,
                                              float* __restrict__ posp) {
    __shared__ __align__(16) bf16_t shB[16384];
    int t = threadIdx.x, w = t >> 6, lane = t & 63;
    int tx = lane & 15, q = lane >> 4;
    int rh = w & 1, ch = w >> 1;
    int bx = blockIdx.x;

    if (bx < NB_INS) {
        // ---- instance branch: A in regs, B staged to LDS, 4-tile chunks ----
        int bid = bx, k = 0, cum = 0;
        while (bid >= cum + 4 * (32 - k)) { cum += 4 * (32 - k); k++; }
        int rem = bid - cum;
        int cc = 32 - k;
        int R = 4 * k + rem / cc;
        int ci = rem - (rem / cc) * cc;
        int c0 = R + ci * 4;
        int ntiles = min(4, 128 - c0);
        int rowBase = R * 128;

        bf16x8 af[4][4];
        load_afrags(embI + ((size_t)R << 14), rh, tx, q, af);

        float rowS[16];
#pragma unroll
        for (int i = 0; i < 16; i++) rowS[i] = 0.f;

        for (int ti = 0; ti < ntiles; ti++) {
            int C = c0 + ti;
            __syncthreads();                       // prior tile's LDS readers done
            stage_panel(embI + ((size_t)C << 14), shB, w, lane);
            __syncthreads();                       // vmcnt drained at barrier
            bool isDiag = (C == R), isPos = (C == R + 64);
            int colBase = C * 128;

            float colS[4] = {0.f, 0.f, 0.f, 0.f};
#pragma unroll
            for (int nt = 0; nt < 4; nt++) {
                bf16x8 bf[4];
#pragma unroll
                for (int ks = 0; ks < 4; ks++)
                    bf[ks] = *(const bf16x8*)(shB + (((ks << 2) + q) << 10) +
                                              ((ch * 64 + nt * 16 + tx) << 3));
                f32x4 acc[4];
#pragma unroll
                for (int rt = 0; rt < 4; rt++) acc[rt] = (f32x4){0.f, 0.f, 0.f, 0.f};
#pragma unroll
                for (int ks = 0; ks < 4; ks++)
#pragma unroll
                    for (int rt = 0; rt < 4; rt++)
                        acc[rt] = __builtin_amdgcn_mfma_f32_16x16x32_bf16(
                            af[rt][ks], bf[ks], acc[rt], 0, 0, 0);
#pragma unroll
                for (int rt = 0; rt < 4; rt++) {
#pragma unroll
                    for (int reg = 0; reg < 4; reg++) {
                        float e = __builtin_amdgcn_exp2f(
                            fmaf(acc[rt][reg], C1_CONST, -C1_CONST));
                        if (isDiag) {
                            int inRow = rh * 64 + rt * 16 + q * 4 + reg;
                            int inCol = ch * 64 + nt * 16 + tx;
                            e = (inRow == inCol) ? 0.f : e;
                        }
                        rowS[rt * 4 + reg] += e;
                        colS[nt] += e;
                    }
                }
                if (isPos && ch == rh) {
                    int reg = tx - q * 4;
                    if (reg >= 0 && reg < 4) {
                        float pl = acc[nt][reg] * 10.0f;   // rt==nt diag fragment
                        atomicAdd(&pos[rowBase + rh * 64 + nt * 16 + tx], pl);
                        atomicAdd(&pos[colBase + rh * 64 + nt * 16 + tx], pl);
                    }
                }
            }
            if (!isDiag) {
#pragma unroll
                for (int i = 0; i < 4; i++) {
                    colS[i] += __shfl_xor(colS[i], 16, 64);
                    colS[i] += __shfl_xor(colS[i], 32, 64);
                }
                if (q == 0) {
#pragma unroll
                    for (int nt = 0; nt < 4; nt++)
                        atomicAdd(&S[colBase + ch * 64 + nt * 16 + tx], colS[nt]);
                }
            }
        }
        flush_rowS(rowS, rowBase, rh, tx, q, S);
    } else {
        // ---- patch branch: one tile per block, register streaming ----
        int pi = bx - NB_INS;
        int b = pi / 10, ti = pi - b * 10;
        int R = RTAB[ti], C = CTAB[ti];
        const bf16_t* base = embP + ((size_t)b << 16);
        float* Sb = Sp + (size_t)b * NP;
        float* pb = posp + (size_t)b * NP;
        bool isDiag = (C == R), isPos = (C == R + 2);
        int rowBase = R * 128, colBase = C * 128;

        bf16x8 af[4][4];
        load_afrags(base + ((size_t)R << 14), rh, tx, q, af);

        float rowS[16];
#pragma unroll
        for (int i = 0; i < 16; i++) rowS[i] = 0.f;
        float colS[4] = {0.f, 0.f, 0.f, 0.f};

        const bf16_t* bbase = base + ((size_t)C << 14) + ((ch * 64 + tx) << 3);
#pragma unroll
        for (int nt = 0; nt < 4; nt++) {
            bf16x8 bf[4];
#pragma unroll
            for (int ks = 0; ks < 4; ks++)
                bf[ks] = *(const bf16x8*)(bbase + (((ks << 2) + q) << 10) + (nt << 7));
            f32x4 acc[4];
#pragma unroll
            for (int rt = 0; rt < 4; rt++) acc[rt] = (f32x4){0.f, 0.f, 0.f, 0.f};
#pragma unroll
            for (int ks = 0; ks < 4; ks++)
#pragma unroll
                for (int rt = 0; rt < 4; rt++)
                    acc[rt] = __builtin_amdgcn_mfma_f32_16x16x32_bf16(
                        af[rt][ks], bf[ks], acc[rt], 0, 0, 0);
#pragma unroll
            for (int rt = 0; rt < 4; rt++) {
#pragma unroll
                for (int reg = 0; reg < 4; reg++) {
                    float e = __builtin_amdgcn_exp2f(
                        fmaf(acc[rt][reg], C1_CONST, -C1_CONST));
                    if (isDiag) {
                        int inRow = rh * 64 + rt * 16 + q * 4 + reg;
                        int inCol = ch * 64 + nt * 16 + tx;
                        e = (inRow == inCol) ? 0.f : e;
                    }
                    rowS[rt * 4 + reg] += e;
                    colS[nt] += e;
                }
            }
            if (isPos && ch == rh) {
                int reg = tx - q * 4;
                if (reg >= 0 && reg < 4) {
                    float pl = acc[nt][reg] * 10.0f;
                    atomicAdd(&pb[rowBase + rh * 64 + nt * 16 + tx], pl);
                    atomicAdd(&pb[colBase + rh * 64 + nt * 16 + tx], pl);
                }
            }
        }
        if (!isDiag) {
#pragma unroll
            for (int i = 0; i < 4; i++) {
                colS[i] += __shfl_xor(colS[i], 16, 64);
                colS[i] += __shfl_xor(colS[i], 32, 64);
            }
            if (q == 0) {
#pragma unroll
                for (int nt = 0; nt < 4; nt++)
                    atomicAdd(&Sb[colBase + ch * 64 + nt * 16 + tx], colS[nt]);
            }
        }
        flush_rowS(rowS, rowBase, rh, tx, q, Sb);
    }
}

// ================= kernel 3: finalize (both losses + last-block combine) =====
__global__ __launch_bounds__(256) void fin_k(const float* __restrict__ S,
                                             const float* __restrict__ pos,
                                             const float* __restrict__ Sp,
                                             const float* __restrict__ posp,
                                             const int* __restrict__ c1,
                                             const int* __restrict__ c2,
                                             float* __restrict__ acc,
                                             float* __restrict__ out) {
    int bx = blockIdx.x, t = threadIdx.x;
    int lane = t & 63, w = t >> 6;
    float va = 0.f, nv = 0.f;
    if (bx < 64) {
        int i = bx * 256 + t;
        va = __logf(S[i]) + 10.0f - pos[i];
    } else {
        int idx = (bx - 64) * 256 + t;   // over BP*NP
        int b = idx >> 9, i = idx & 511;
        int cnt = (i < P) ? c1[b * P + i] : c2[b * P + i - P];
        bool valid = (cnt != 0);
        va = valid ? (__logf(Sp[idx]) + 10.0f - posp[idx]) : 0.f;
        nv = valid ? 1.0f : 0.0f;
    }
#pragma unroll
    for (int off = 32; off >= 1; off >>= 1) {
        va += __shfl_down(va, off, 64);
        nv += __shfl_down(nv, off, 64);
    }
    __shared__ float ps[4], pn[4];
    if (lane == 0) { ps[w] = va; pn[w] = nv; }
    __syncthreads();
    if (t == 0) {
        float sv = ps[0] + ps[1] + ps[2] + ps[3];
        float sn = pn[0] + pn[1] + pn[2] + pn[3];
        if (bx < 64) {
            atomicAdd(&acc[0], sv);
        } else {
            atomicAdd(&acc[1], sv);
            atomicAdd(&acc[2], sn);
        }
        __threadfence();
        unsigned old = atomicAdd((unsigned*)&acc[3], 1u);
        if (old == NB_FIN - 1) {
            float a0 = atomicAdd(&acc[0], 0.0f);
            float a1 = atomicAdd(&acc[1], 0.0f);
            float a2 = atomicAdd(&acc[2], 0.0f);
            out[0] = a0 * (1.0f / (float)N_INS) + a1 / a2;
        }
    }
}

// ---------------- launch ----------------
extern "C" void kernel_launch(void* const* d_in, const int* in_sizes, int n_in,
                              void* d_out, int out_size, void* d_ws, size_t ws_size,
                              hipStream_t stream) {
    const float* v1i = (const float*)d_in[0];
    const float* v2i = (const float*)d_in[1];
    const float* v1p = (const float*)d_in[2];
    const float* v2p = (const float*)d_in[3];
    const int* c1 = (const int*)d_in[4];
    const int* c2 = (const int*)d_in[5];
    float* ws = (float*)d_ws;
    float* out = (float*)d_out;
    bf16_t* embI = (bf16_t*)((char*)d_ws + EMB_I_BYTE);
    bf16_t* embP = (bf16_t*)((char*)d_ws + EMB_P_BYTE);

    prep_k<<<NB_PREP, 256, 0, stream>>>(v1i, v2i, v1p, v2p, embI, embP, ws);
    gram_k<<<NB_GRAM, 256, 0, stream>>>(embI, embP, ws + WS_S, ws + WS_POS,
                                        ws + WS_SP, ws + WS_PP);
    fin_k<<<NB_FIN, 256, 0, stream>>>(ws + WS_S, ws + WS_POS, ws + WS_SP,
                                      ws + WS_PP, c1, c2, ws + WS_ACC, out);
}

// Round 8
// 221.875 us; speedup vs baseline: 1.8357x; 1.2012x over previous
//
#include <hip/hip_runtime.h>
#include <math.h>

typedef __bf16 bf16_t;
typedef __bf16 bf16x8 __attribute__((ext_vector_type(8)));
typedef float f32x4 __attribute__((ext_vector_type(4)));
typedef float f32x2 __attribute__((ext_vector_type(2)));

#define B_INS 8192
#define N_INS 16384
#define D 128
#define BP 256
#define P 256
#define NP 512

// exp(l-10) with l = dot*10  ==  exp2(dot*C1 - C1), C1 = 10*log2(e)
#define C1_CONST 14.426950408889634f

// ---------------- workspace layout (floats) ----------------
// acc[0]=ins sum, acc[1]=patch sum, acc[2]=n_valid, acc[3]=ticket (unused now)
#define WS_ACC 0
#define WS_S 8
#define WS_POS (8 + 16384)
#define WS_SP (8 + 2 * 16384)
#define WS_PP (WS_SP + BP * NP)
#define WS_ZERO_FLOATS (WS_PP + BP * NP)        // 294920 floats = 73730 float4 exactly
#define EMB_I_BYTE ((((WS_ZERO_FLOATS) * 4 + 15) / 16) * 16)
#define EMB_P_BYTE (EMB_I_BYTE + N_INS * D * 2)

// Panel layout: global row i, k -> panel p=i>>7, r=i&127, g=k>>3, j=k&7
// elem offset = (p<<14) + (g<<10) + (r<<3) + j. One panel = 32 KB contiguous.
// - register frag loads: 16 tx-lanes at 16B stride -> contiguous 256B runs.
// - LDS ds_read_b128 at (g<<10)+(r<<3): banks (r*4+c)%32, conflict-free (R4-verified).

// grid partitioning
#define NB_NORMI 128        // one block per ins panel
#define NB_NORMP 2048
#define NB_ZERO 289
#define NB_PREP (NB_NORMI + NB_NORMP + NB_ZERO)
#define NB_INS 1088         // ins: (R, chunk of 8 C-panels), octet decode
#define NB_PATCHB 1024      // patch: (batch, R-panel), C = R..3
#define NB_GRAM (NB_INS + NB_PATCHB)
#define NB_FIN 576          // 64 ins + 512 patch

// ---------------- staging: linear 32 KB panel copy (async, wave-uniform dst) ----
__device__ __forceinline__ void load_lds16(const bf16_t* g, bf16_t* l) {
    __builtin_amdgcn_global_load_lds(
        (const __attribute__((address_space(1))) void*)g,
        (__attribute__((address_space(3))) void*)l, 16, 0, 0);
}

__device__ __forceinline__ void stage_panel(const bf16_t* __restrict__ src,
                                            bf16_t* dst, int w, int lane) {
    const bf16_t* g = src + w * 4096 + lane * 8;
    bf16_t* d = dst + w * 4096;
#pragma unroll
    for (int it = 0; it < 8; it++)
        load_lds16(g + it * 512, d + it * 512);
}

// ---------------- A-fragment register load (from L2, panel layout) -----------
__device__ __forceinline__ void load_afrags(const bf16_t* __restrict__ abase,
                                            int rh, int tx, int q, bf16x8 af[4][4]) {
    const bf16_t* a = abase + ((rh * 64 + tx) << 3);
#pragma unroll
    for (int rt = 0; rt < 4; rt++)
#pragma unroll
        for (int ks = 0; ks < 4; ks++)
            af[rt][ks] = *(const bf16x8*)(a + (((ks << 2) + q) << 10) + (rt << 7));
}

// ================= kernel 1: prep (norms + workspace zero) =================
__global__ __launch_bounds__(256) void prep_k(const float* __restrict__ v1i,
                                              const float* __restrict__ v2i,
                                              const float* __restrict__ v1p,
                                              const float* __restrict__ v2p,
                                              bf16_t* __restrict__ embI,
                                              bf16_t* __restrict__ embP,
                                              float* __restrict__ ws) {
    __shared__ float L[128][65];
    __shared__ float ps[4][64];
    __shared__ float invs[128];
    int bx = blockIdx.x;
    int t = threadIdx.x;
    if (bx < NB_NORMI) {
        // one block per 128-row ins panel; panels 0..63 from v1i, 64..127 from v2i
        int p = bx;
        const float* srcP = (p < 64) ? (v1i + (size_t)p * 128 * D)
                                     : (v2i + (size_t)(p - 64) * 128 * D);
        // phase 1: per-row inv norms (2 threads per row)
        {
            int r = t >> 1, h = t & 1;
            const float* row = srcP + (size_t)r * D + h * 64;
            float ss = 0.f;
#pragma unroll
            for (int j = 0; j < 16; j++) {
                float4 v = *(const float4*)(row + j * 4);
                ss += v.x * v.x + v.y * v.y + v.z * v.z + v.w * v.w;
            }
            ss += __shfl_xor(ss, 1, 64);
            if (h == 0) invs[r] = 1.0f / fmaxf(sqrtf(ss), 1e-12f);
        }
        __syncthreads();
        // phase 2: re-read (L2-hot), scale, 16B coalesced panel-layout stores
#pragma unroll
        for (int it = 0; it < 8; it++) {
            int idx = it * 256 + t;
            int r = idx & 127, g = idx >> 7;
            const float* src8 = srcP + (size_t)r * D + g * 8;
            float4 a = *(const float4*)(src8);
            float4 b = *(const float4*)(src8 + 4);
            float inv = invs[r];
            bf16x8 v;
            v[0] = (bf16_t)(a.x * inv); v[1] = (bf16_t)(a.y * inv);
            v[2] = (bf16_t)(a.z * inv); v[3] = (bf16_t)(a.w * inv);
            v[4] = (bf16_t)(b.x * inv); v[5] = (bf16_t)(b.y * inv);
            v[6] = (bf16_t)(b.z * inv); v[7] = (bf16_t)(b.w * inv);
            *(bf16x8*)(embI + ((size_t)p << 14) + (g << 10) + (r << 3)) = v;
        }
    } else if (bx < NB_NORMI + NB_NORMP) {
        int bx2 = bx - NB_NORMI;
        int b = bx2 >> 3, h = (bx2 >> 2) & 1, chunk = bx2 & 3;
        int i0 = chunk * 64;
        const float* src = ((h == 0) ? v1p : v2p) + (size_t)b * D * P;
#pragma unroll
        for (int it = 0; it < 8; it++) {
            int fi = it * 256 + t;
            int d = fi >> 4, c4 = fi & 15;
            float4 v = *(const float4*)(src + (size_t)d * P + i0 + c4 * 4);
            L[d][c4 * 4 + 0] = v.x;
            L[d][c4 * 4 + 1] = v.y;
            L[d][c4 * 4 + 2] = v.z;
            L[d][c4 * 4 + 3] = v.w;
        }
        __syncthreads();
        {
            int col = t & 63, part = t >> 6;
            float ss = 0.f;
#pragma unroll 8
            for (int d = part * 32; d < part * 32 + 32; d++) { float x = L[d][col]; ss += x * x; }
            ps[part][col] = ss;
        }
        __syncthreads();
        if (t < 64) {
            float n2 = ps[0][t] + ps[1][t] + ps[2][t] + ps[3][t];
            invs[t] = 1.0f / fmaxf(sqrtf(n2), 1e-12f);
        }
        __syncthreads();
        // 16B coalesced panel-layout stores: lanes sweep ic (contiguous runs)
#pragma unroll
        for (int it = 0; it < 4; it++) {
            int idx = it * 256 + t;
            int ic = idx & 63, g = idx >> 6;
            float inv = invs[ic];
            bf16x8 v;
#pragma unroll
            for (int j = 0; j < 8; j++) v[j] = (bf16_t)(L[g * 8 + j][ic] * inv);
            int iLoc = h * P + i0 + ic;
            *(bf16x8*)(embP + ((size_t)b << 16) + ((size_t)(iLoc >> 7) << 14) +
                       (g << 10) + ((iLoc & 127) << 3)) = v;
        }
    } else {
        int idx = (bx - NB_NORMI - NB_NORMP) * 256 + t;
        if (idx < WS_ZERO_FLOATS / 4)
            ((f32x4*)ws)[idx] = (f32x4){0.f, 0.f, 0.f, 0.f};
    }
}

// ================= kernel 2: unified Gram (ins + patch), dbuf pipeline ========
__global__ __launch_bounds__(256) void gram_k(const bf16_t* __restrict__ embI,
                                              const bf16_t* __restrict__ embP,
                                              float* __restrict__ S,
                                              float* __restrict__ pos,
                                              float* __restrict__ Sp,
                                              float* __restrict__ posp) {
    __shared__ __align__(16) bf16_t shB[2][16384];
    int t = threadIdx.x, w = t >> 6, lane = t & 63;
    int tx = lane & 15, q = lane >> 4;
    int rh = w & 1, ch = w >> 1;
    int bx = blockIdx.x;

    const bf16_t *Abase, *Bbase;
    float *Sarr, *posArr;
    int R, c0, n, diagC, posC;
    if (bx < NB_INS) {
        // octet decode: R in octet k has ceil((128-R)/8) = 16-k chunks of 8
        int bid = bx, k = 0, cum = 0;
        while (bid >= cum + 8 * (16 - k)) { cum += 8 * (16 - k); k++; }
        int rem = bid - cum, cc = 16 - k;
        R = 8 * k + rem / cc;
        int ci = rem - (rem / cc) * cc;
        c0 = R + ci * 8;
        n = min(8, 128 - c0);
        Abase = embI + ((size_t)R << 14);
        Bbase = embI;
        Sarr = S; posArr = pos;
        diagC = R; posC = R + 64;
    } else {
        int pi = bx - NB_INS;
        int b = pi >> 2; R = pi & 3;
        c0 = R; n = 4 - R;
        const bf16_t* base = embP + ((size_t)b << 16);
        Abase = base + ((size_t)R << 14);
        Bbase = base;
        Sarr = Sp + (size_t)b * NP; posArr = posp + (size_t)b * NP;
        diagC = R; posC = R + 2;            // pos pairs (0,2),(1,3); R>=2 has none
    }
    int rowBase = R * 128;

    bf16x8 af[4][4];
    load_afrags(Abase, rh, tx, q, af);

    f32x2 rowS2[8];
#pragma unroll
    for (int i = 0; i < 8; i++) rowS2[i] = (f32x2){0.f, 0.f};

    stage_panel(Bbase + ((size_t)c0 << 14), shB[0], w, lane);
    int cur = 0;
    for (int ti = 0; ti < n; ti++) {
        int C = c0 + ti;
        __syncthreads();   // drains vmcnt: buf[cur] staged; prior readers of buf[cur^1] done
        if (ti + 1 < n)    // prefetch next panel into the other buffer (drained next iter)
            stage_panel(Bbase + ((size_t)(C + 1) << 14), shB[cur ^ 1], w, lane);
        bool isDiag = (C == diagC), isPos = (C == posC);
        int colBase = C * 128;
        const bf16_t* sb = shB[cur];

        float colS[4];
#pragma unroll
        for (int nt = 0; nt < 4; nt++) {
            bf16x8 bf[4];
#pragma unroll
            for (int ks = 0; ks < 4; ks++)
                bf[ks] = *(const bf16x8*)(sb + (((ks << 2) + q) << 10) +
                                          ((ch * 64 + nt * 16 + tx) << 3));
            f32x4 acc[4];
#pragma unroll
            for (int rt = 0; rt < 4; rt++) acc[rt] = (f32x4){0.f, 0.f, 0.f, 0.f};
#pragma unroll
            for (int ks = 0; ks < 4; ks++)
#pragma unroll
                for (int rt = 0; rt < 4; rt++)
                    acc[rt] = __builtin_amdgcn_mfma_f32_16x16x32_bf16(
                        af[rt][ks], bf[ks], acc[rt], 0, 0, 0);

            // packed epilogue: f32x2 lanes -> v_pk_fma/v_pk_add
            f32x2 cs = (f32x2){0.f, 0.f};
#pragma unroll
            for (int rt = 0; rt < 4; rt++) {
                f32x2 l0 = {acc[rt][0], acc[rt][1]};
                f32x2 l1 = {acc[rt][2], acc[rt][3]};
                l0 = l0 * C1_CONST - C1_CONST;
                l1 = l1 * C1_CONST - C1_CONST;
                f32x2 e0 = {__builtin_amdgcn_exp2f(l0.x), __builtin_amdgcn_exp2f(l0.y)};
                f32x2 e1 = {__builtin_amdgcn_exp2f(l1.x), __builtin_amdgcn_exp2f(l1.y)};
                if (isDiag) {
                    int inRow = rh * 64 + rt * 16 + q * 4;
                    int inCol = ch * 64 + nt * 16 + tx;
                    if (inRow + 0 == inCol) e0.x = 0.f;
                    if (inRow + 1 == inCol) e0.y = 0.f;
                    if (inRow + 2 == inCol) e1.x = 0.f;
                    if (inRow + 3 == inCol) e1.y = 0.f;
                }
                rowS2[rt * 2] += e0;
                rowS2[rt * 2 + 1] += e1;
                cs += e0 + e1;
            }
            colS[nt] = cs.x + cs.y;

            if (isPos && ch == rh) {
                int reg = tx - q * 4;
                if (reg >= 0 && reg < 4) {
                    float pl = acc[nt][reg] * 10.0f;   // rt==nt diagonal fragment
                    atomicAdd(&posArr[rowBase + rh * 64 + nt * 16 + tx], pl);
                    atomicAdd(&posArr[colBase + rh * 64 + nt * 16 + tx], pl);
                }
            }
        }
        if (!isDiag) {
#pragma unroll
            for (int i = 0; i < 4; i++) {
                colS[i] += __shfl_xor(colS[i], 16, 64);
                colS[i] += __shfl_xor(colS[i], 32, 64);
            }
            if (q == 0) {
#pragma unroll
                for (int nt = 0; nt < 4; nt++)
                    atomicAdd(&Sarr[colBase + ch * 64 + nt * 16 + tx], colS[nt]);
            }
        }
        cur ^= 1;
    }
    // flush rowS: reduce over 16 tx lanes, one atomic per row
    float* rowS = (float*)rowS2;   // [rt*4 + reg]
#pragma unroll
    for (int off = 1; off <= 8; off <<= 1)
#pragma unroll
        for (int i = 0; i < 16; i++) rowS[i] += __shfl_xor(rowS[i], off, 16);
    if (tx == 0) {
#pragma unroll
        for (int rt = 0; rt < 4; rt++)
#pragma unroll
            for (int reg = 0; reg < 4; reg++)
                atomicAdd(&Sarr[rowBase + rh * 64 + rt * 16 + q * 4 + reg],
                          rowS[rt * 4 + reg]);
    }
}

// ================= kernel 3: finalize =================
__global__ __launch_bounds__(256) void fin_k(const float* __restrict__ S,
                                             const float* __restrict__ pos,
                                             const float* __restrict__ Sp,
                                             const float* __restrict__ posp,
                                             const int* __restrict__ c1,
                                             const int* __restrict__ c2,
                                             float* __restrict__ acc,
                                             float* __restrict__ out) {
    int bx = blockIdx.x, t = threadIdx.x;
    int lane = t & 63, w = t >> 6;
    float va = 0.f, nv = 0.f;
    if (bx < 64) {
        int i = bx * 256 + t;
        va = __logf(S[i]) + 10.0f - pos[i];
    } else {
        int idx = (bx - 64) * 256 + t;   // over BP*NP
        int b = idx >> 9, i = idx & 511;
        int cnt = (i < P) ? c1[b * P + i] : c2[b * P + i - P];
        bool valid = (cnt != 0);
        va = valid ? (__logf(Sp[idx]) + 10.0f - posp[idx]) : 0.f;
        nv = valid ? 1.0f : 0.0f;
    }
#pragma unroll
    for (int off = 32; off >= 1; off >>= 1) {
        va += __shfl_down(va, off, 64);
        nv += __shfl_down(nv, off, 64);
    }
    __shared__ float ps[4], pn[4];
    if (lane == 0) { ps[w] = va; pn[w] = nv; }
    __syncthreads();
    if (t == 0) {
        float sv = ps[0] + ps[1] + ps[2] + ps[3];
        float sn = pn[0] + pn[1] + pn[2] + pn[3];
        if (bx < 64) {
            atomicAdd(&acc[0], sv);
        } else {
            atomicAdd(&acc[1], sv);
            atomicAdd(&acc[2], sn);
        }
        __threadfence();
        unsigned old = atomicAdd((unsigned*)&acc[3], 1u);
        if (old == NB_FIN - 1) {
            float a0 = atomicAdd(&acc[0], 0.0f);
            float a1 = atomicAdd(&acc[1], 0.0f);
            float a2 = atomicAdd(&acc[2], 0.0f);
            out[0] = a0 * (1.0f / (float)N_INS) + a1 / a2;
        }
    }
}

// ---------------- launch ----------------
extern "C" void kernel_launch(void* const* d_in, const int* in_sizes, int n_in,
                              void* d_out, int out_size, void* d_ws, size_t ws_size,
                              hipStream_t stream) {
    const float* v1i = (const float*)d_in[0];
    const float* v2i = (const float*)d_in[1];
    const float* v1p = (const float*)d_in[2];
    const float* v2p = (const float*)d_in[3];
    const int* c1 = (const int*)d_in[4];
    const int* c2 = (const int*)d_in[5];
    float* ws = (float*)d_ws;
    float* out = (float*)d_out;
    bf16_t* embI = (bf16_t*)((char*)d_ws + EMB_I_BYTE);
    bf16_t* embP = (bf16_t*)((char*)d_ws + EMB_P_BYTE);

    prep_k<<<NB_PREP, 256, 0, stream>>>(v1i, v2i, v1p, v2p, embI, embP, ws);
    gram_k<<<NB_GRAM, 256, 0, stream>>>(embI, embP, ws + WS_S, ws + WS_POS,
                                        ws + WS_SP, ws + WS_PP);
    fin_k<<<NB_FIN, 256, 0, stream>>>(ws + WS_S, ws + WS_POS, ws + WS_SP,
                                      ws + WS_PP, c1, c2, ws + WS_ACC, out);
}